// Round 2
// baseline (105.252 us; speedup 1.0000x reference)
//
#include <hip/hip_runtime.h>
#include <math.h>

// EfficientByteMUL: fused decode -> collapsed tiny-MLP -> patch+copy.
// One half-wave (32 lanes) per token row of 128 floats; lane c holds float4
// elements 4c..4c+3 -> every wave-level load/store is a coalesced 1KB segment.
// R1 change: 4 row loads issued up front per half-wave (MLP latency hiding),
// nontemporal load/store hints (streaming data, no reuse).

#define HID 256

typedef float f4 __attribute__((ext_vector_type(4)));

__device__ __forceinline__ f4 process_token(
    f4 v, int c,
    const float* __restrict__ r0, const float* __restrict__ r1,
    const float* __restrict__ r29, const float* __restrict__ rb1,
    const float* __restrict__ w2c, float b2v)
{
    // ---- mask (elements 0,1 live in lane c==0) ----
    int valid = (v.x >= 0.5f) && (v.y >= 0.5f);
    const int mval = __shfl(valid, 0, 32);

    // ---- local argmax over this lane's 4 elements ----
    // fields: lanes 4..7 -> a_lo, 8..11 -> a_hi, 12..15 -> b_lo, 16..19 -> b_hi
    const int fi = (c & 3) << 2;
    float m = v.x; int g = fi;
    if (v.y > m) { m = v.y; g = fi + 1; }
    if (v.z > m) { m = v.z; g = fi + 2; }
    if (v.w > m) { m = v.w; g = fi + 3; }
    // butterfly across the 4-lane group; tie -> lowest index (matches jnp.argmax)
    {
        float om = __shfl_xor(m, 1, 32);
        int   og = __shfl_xor(g, 1, 32);
        if (om > m || (om == m && og < g)) { m = om; g = og; }
        om = __shfl_xor(m, 2, 32);
        og = __shfl_xor(g, 2, 32);
        if (om > m || (om == m && og < g)) { m = om; g = og; }
    }
    const int a_lo = __shfl(g, 4, 32);
    const int a_hi = __shfl(g, 8, 32);
    const int b_lo = __shfl(g, 12, 32);
    const int b_hi = __shfl(g, 16, 32);

    int res = 0;
    if (__ballot(mval)) {   // skip MLP when both tokens of this wave are unmasked
        const float af = (float)(a_lo | (a_hi << 4));
        const float bf = (float)(b_lo | (b_hi << 4));
        double acc = 0.0;
        #pragma unroll
        for (int k = 0; k < 8; ++k) {
            float t = af * r0[k];      // keep exact op order of the R0-verified kernel
            t += bf * r1[k];
            t += r29[k];
            t += rb1[k];
            t = fmaxf(t, 0.0f);
            acc = fma((double)t, (double)w2c[k], acc);
        }
        acc += __shfl_xor(acc, 16, 32);
        acc += __shfl_xor(acc,  8, 32);
        acc += __shfl_xor(acc,  4, 32);
        acc += __shfl_xor(acc,  2, 32);
        acc += __shfl_xor(acc,  1, 32);
        const double y = acc + (double)b2v;
        res = ((int)rint(y)) & 255;    // rint = half-to-even, matches np.round
    }

    // ---- patch ----
    const int t_lo = 80 + (res & 15);
    const int t_hi = 96 + ((res >> 4) & 15);
    const float addv = mval ? 2.0f : 0.0f;
    const int e0 = c << 2;
    v.x += (e0     == t_lo || e0     == t_hi) ? addv : 0.0f;
    v.y += (e0 + 1 == t_lo || e0 + 1 == t_hi) ? addv : 0.0f;
    v.z += (e0 + 2 == t_lo || e0 + 2 == t_hi) ? addv : 0.0f;
    v.w += (e0 + 3 == t_lo || e0 + 3 == t_hi) ? addv : 0.0f;
    return v;
}

__global__ __launch_bounds__(256) void ebm_fused_kernel(
    const float* __restrict__ x,    // [tokens,128]
    const float* __restrict__ W1,   // [64,256] row-major
    const float* __restrict__ b1,   // [256]
    const float* __restrict__ W2,   // [256,64] row-major
    const float* __restrict__ b2,   // [64]
    float* __restrict__ out,        // [tokens,128]
    int tokens)
{
    const int tid = threadIdx.x;
    const int c = tid & 31;

    // per-lane weight slices, j = c + 32*k (coalesced, register-resident)
    float r0[8], r1[8], r29[8], rb1[8], w2c[8];
    #pragma unroll
    for (int k = 0; k < 8; ++k) {
        const int j = c + 32 * k;
        r0[k]  = W1[j];
        r1[k]  = W1[HID + j];
        r29[k] = W1[29 * HID + j];
        rb1[k] = b1[j];
        w2c[k] = W2[j * 64 + 40];
    }
    const float b2v = b2[40];

    const int nHW = (gridDim.x * blockDim.x) >> 5;       // total half-waves
    const int hw0 = (blockIdx.x * blockDim.x + tid) >> 5;

    const f4* __restrict__ in4  = (const f4*)x;
    f4*       __restrict__ out4 = (f4*)out;

    int tok = hw0;
    // main: 4 rows in flight per half-wave
    for (; tok + 3 * nHW < tokens; tok += 4 * nHW) {
        const int i0 = tok * 32 + c;
        const int s  = nHW * 32;
        f4 v0 = __builtin_nontemporal_load(in4 + i0);
        f4 v1 = __builtin_nontemporal_load(in4 + i0 + s);
        f4 v2 = __builtin_nontemporal_load(in4 + i0 + 2 * s);
        f4 v3 = __builtin_nontemporal_load(in4 + i0 + 3 * s);
        v0 = process_token(v0, c, r0, r1, r29, rb1, w2c, b2v);
        __builtin_nontemporal_store(v0, out4 + i0);
        v1 = process_token(v1, c, r0, r1, r29, rb1, w2c, b2v);
        __builtin_nontemporal_store(v1, out4 + i0 + s);
        v2 = process_token(v2, c, r0, r1, r29, rb1, w2c, b2v);
        __builtin_nontemporal_store(v2, out4 + i0 + 2 * s);
        v3 = process_token(v3, c, r0, r1, r29, rb1, w2c, b2v);
        __builtin_nontemporal_store(v3, out4 + i0 + 3 * s);
    }
    // tail
    for (; tok < tokens; tok += nHW) {
        const int i0 = tok * 32 + c;
        f4 v = __builtin_nontemporal_load(in4 + i0);
        v = process_token(v, c, r0, r1, r29, rb1, w2c, b2v);
        __builtin_nontemporal_store(v, out4 + i0);
    }
}

extern "C" void kernel_launch(void* const* d_in, const int* in_sizes, int n_in,
                              void* d_out, int out_size, void* d_ws, size_t ws_size,
                              hipStream_t stream) {
    const float* x  = (const float*)d_in[0];
    const float* W1 = (const float*)d_in[1];
    const float* b1 = (const float*)d_in[2];
    const float* W2 = (const float*)d_in[3];
    const float* b2 = (const float*)d_in[4];
    float* out = (float*)d_out;

    const int tokens = in_sizes[0] / 128;   // 8*8192 = 65536

    const int block = 256;                  // 8 half-waves per block
    const int grid  = 2048;                 // 16384 half-waves -> 4 tokens each
    ebm_fused_kernel<<<grid, block, 0, stream>>>(x, W1, b1, W2, b2, out, tokens);
}

// Round 3
// 102.663 us; speedup vs baseline: 1.0252x; 1.0252x over previous
//
#include <hip/hip_runtime.h>
#include <math.h>

// EfficientByteMUL: fused decode -> collapsed tiny-MLP -> patch+copy.
// One half-wave (32 lanes) per token row of 128 floats; lane c holds float4
// elements 4c..4c+3 -> every wave-level load/store is a coalesced 1KB segment.
// R2: revert nontemporal (R1 regression); ballot-based argmax (shorter DS
// chain); one token per half-wave (no grid-stride loop, 32 waves/CU).

#define HID 256

typedef float f4 __attribute__((ext_vector_type(4)));

__global__ __launch_bounds__(256) void ebm_fused_kernel(
    const float* __restrict__ x,    // [tokens,128]
    const float* __restrict__ W1,   // [64,256] row-major
    const float* __restrict__ b1,   // [256]
    const float* __restrict__ W2,   // [256,64] row-major
    const float* __restrict__ b2,   // [64]
    float* __restrict__ out,        // [tokens,128]
    int tokens)
{
    const int tid  = threadIdx.x;
    const int c    = tid & 31;                   // column within token row
    const int tok  = (blockIdx.x * blockDim.x + tid) >> 5;
    if (tok >= tokens) return;

    const f4* __restrict__ in4  = (const f4*)x;
    f4*       __restrict__ out4 = (f4*)out;

    const int idx = tok * 32 + c;
    f4 v = in4[idx];                             // coalesced 1KB per half-wave

    // ---- per-lane weight slices, j = c + 32*k (coalesced, register-resident) ----
    float r0[8], r1[8], r29[8], rb1[8], w2c[8];
    #pragma unroll
    for (int k = 0; k < 8; ++k) {
        const int j = c + 32 * k;
        r0[k]  = W1[j];                          // W1[0, j]
        r1[k]  = W1[HID + j];                    // W1[1, j]
        r29[k] = W1[29 * HID + j];               // W1[29, j]
        rb1[k] = b1[j];
        w2c[k] = W2[j * 64 + 40];                // W2[j, 40]
    }
    const float b2v = b2[40];

    // ---- mask (elements 0,1 live in lane c==0) ----
    int valid = (v.x >= 0.5f) && (v.y >= 0.5f);
    const int mval = __shfl(valid, 0, 32);

    // ---- local argmax over this lane's 4 elements (strict >, lowest idx on tie) ----
    // fields: lanes 4..7 -> a_lo, 8..11 -> a_hi, 12..15 -> b_lo, 16..19 -> b_hi
    const int fi = (c & 3) << 2;                 // field-local index of v.x
    float m = v.x; int g = fi;
    if (v.y > m) { m = v.y; g = fi + 1; }
    if (v.z > m) { m = v.z; g = fi + 2; }
    if (v.w > m) { m = v.w; g = fi + 3; }

    // group max (value only) across the 4-lane group: 2-round butterfly
    float mm = m;
    mm = fmaxf(mm, __shfl_xor(mm, 1, 32));
    mm = fmaxf(mm, __shfl_xor(mm, 2, 32));

    // wave-wide ballot of "this lane holds its group's max"; every lane can
    // then find each field's winning lane (lowest lane on tie -> lowest index,
    // since each lane's local argmax is already its lowest max index)
    const unsigned long long bal = __ballot(m == mm);
    const int hwb = tid & 32;                    // this half-wave's lane-id base
    const int w0 = 4  + __builtin_ctz((unsigned)(bal >> (hwb + 4))  & 0xFu);
    const int w1 = 8  + __builtin_ctz((unsigned)(bal >> (hwb + 8))  & 0xFu);
    const int w2 = 12 + __builtin_ctz((unsigned)(bal >> (hwb + 12)) & 0xFu);
    const int w3 = 16 + __builtin_ctz((unsigned)(bal >> (hwb + 16)) & 0xFu);
    const int a_lo = __shfl(g, w0, 32);
    const int a_hi = __shfl(g, w1, 32);
    const int b_lo = __shfl(g, w2, 32);
    const int b_hi = __shfl(g, w3, 32);

    int res = 0;
    if (__ballot(mval)) {                        // skip MLP if whole wave unmasked
        const float af = (float)(a_lo | (a_hi << 4));
        const float bf = (float)(b_lo | (b_hi << 4));
        double acc = 0.0;
        #pragma unroll
        for (int k = 0; k < 8; ++k) {
            float t = af * r0[k];                // exact op order of verified R0
            t += bf * r1[k];
            t += r29[k];
            t += rb1[k];
            t = fmaxf(t, 0.0f);
            acc = fma((double)t, (double)w2c[k], acc);
        }
        acc += __shfl_xor(acc, 16, 32);
        acc += __shfl_xor(acc,  8, 32);
        acc += __shfl_xor(acc,  4, 32);
        acc += __shfl_xor(acc,  2, 32);
        acc += __shfl_xor(acc,  1, 32);
        const double y = acc + (double)b2v;
        res = ((int)rint(y)) & 255;              // rint = half-to-even = np.round
    }

    // ---- patch + store ----
    const int t_lo = 80 + (res & 15);
    const int t_hi = 96 + ((res >> 4) & 15);
    const float addv = mval ? 2.0f : 0.0f;
    const int e0 = c << 2;
    v.x += (e0     == t_lo || e0     == t_hi) ? addv : 0.0f;
    v.y += (e0 + 1 == t_lo || e0 + 1 == t_hi) ? addv : 0.0f;
    v.z += (e0 + 2 == t_lo || e0 + 2 == t_hi) ? addv : 0.0f;
    v.w += (e0 + 3 == t_lo || e0 + 3 == t_hi) ? addv : 0.0f;

    out4[idx] = v;
}

extern "C" void kernel_launch(void* const* d_in, const int* in_sizes, int n_in,
                              void* d_out, int out_size, void* d_ws, size_t ws_size,
                              hipStream_t stream) {
    const float* x  = (const float*)d_in[0];
    const float* W1 = (const float*)d_in[1];
    const float* b1 = (const float*)d_in[2];
    const float* W2 = (const float*)d_in[3];
    const float* b2 = (const float*)d_in[4];
    float* out = (float*)d_out;

    const int tokens = in_sizes[0] / 128;        // 8*8192 = 65536

    const int block = 256;                       // 8 half-waves per block
    const int grid  = (tokens * 32 + block - 1) / block;   // one token per half-wave
    ebm_fused_kernel<<<grid, block, 0, stream>>>(x, W1, b1, W2, b2, out, tokens);
}